// Round 1
// 297.290 us; speedup vs baseline: 1.0076x; 1.0076x over previous
//
#include <hip/hip_runtime.h>
#include <hip/hip_bf16.h>
#include <math.h>

// ---------------------------------------------------------------------------
// GAT 2-layer forward. CSR aggregation, bf16 gather table, inline attention
// weights. This revision replaces the fp32 VALU GEMM with an LDS-free bf16
// MFMA GEMM (mfma_f32_16x16x32_bf16):
//
//   0) init_ws: zero cursor + Z, convert W1/W2 -> bf16 workspace copies
//   1) gemm_mfma<128>: blocks[0,ntiles) = MFMA gemm1 (A-frags converted from
//      fp32 x in-register, B-frags straight from L1/L2-resident bf16 W);
//      blocks[ntiles,+1264) = dst-histogram over real edges.
//   2) scan_blocks, 3) scan_finish (rowptr prefix; cursor copy)
//   4) scatter_z: blocks[0,256)=z1 edge-parallel; rest dst-partitioned scatter
//   5) csr_aggregate -> x2 (self-loop term inline; relu fused)
//   6) gemm_mfma<64> grid=ntiles (pure gemm2)
//   7) z_edge -> Z[2..3]
//   8) csr_aggregate -> out
//
// MFMA layout (HW-verified m89): A: lane holds A[l&15][(l>>4)*8+j];
// B: B[(l>>4)*8+j][l&15]; D: row=(l>>4)*4+reg, col=l&15.
// Wave w owns rows [w*16, w*16+16) x all 128 cols (8 col-tiles), K resident
// in fragments (no LDS, no syncthreads, zero bank conflicts).
// ---------------------------------------------------------------------------

#define NHIST 1264   // 8*158
#define NZ    256
#define NSCAT 1792   // 8*224

using short8 = __attribute__((ext_vector_type(8))) short;
using f32x4  = __attribute__((ext_vector_type(4))) float;

__device__ __forceinline__ unsigned f2bf(float x) {  // fp32 -> bf16 (RNE)
  unsigned u = __float_as_uint(x);
  return (u + 0x7fffu + ((u >> 16) & 1u)) >> 16;
}
__device__ __forceinline__ float bflo(unsigned p) { return __uint_as_float(p << 16); }
__device__ __forceinline__ float bfhi(unsigned p) { return __uint_as_float(p & 0xffff0000u); }

// zero the cursor/deg array + Z accumulators; convert W1/W2 to bf16 copies
__global__ __launch_bounds__(256) void init_ws(
    const float* __restrict__ W1, const float* __restrict__ W2,
    unsigned short* __restrict__ wbf1, unsigned short* __restrict__ wbf2,
    int* __restrict__ cursor, float* __restrict__ Z, int N) {
  int tid = blockIdx.x * 256 + threadIdx.x;
  int stride = gridDim.x * 256;
  for (int i = tid; i < N; i += stride) cursor[i] = 0;
  for (int i = tid; i < 128 * 128; i += stride)
    wbf1[i] = (unsigned short)f2bf(W1[i]);
  for (int i = tid; i < 128 * 64; i += stride)
    wbf2[i] = (unsigned short)f2bf(W2[i]);
  if (tid < 4) Z[tid] = 0.f;
}

// LDS-free MFMA GEMM (h = x @ W^T) + fused attention scores + bf16 pack.
// blocks >= ntiles run the dst-histogram (layer 1 only).
template <int FIN>
__global__ __launch_bounds__(256) void gemm_mfma(
    const float* __restrict__ x, const unsigned short* __restrict__ Wb,
    const float* __restrict__ att, unsigned* __restrict__ hq,
    float* __restrict__ si, float* __restrict__ sj,
    int N,
    const int* __restrict__ dstE, int* __restrict__ deg,
    int E, int ntiles, int step) {
  const int tid = threadIdx.x;

  if ((int)blockIdx.x >= ntiles) {
    // ---- histogram over real edges (dst-partitioned, %8 XCD-affine) ----
    int bid = blockIdx.x - ntiles;
    int p = bid & 7, sub = bid >> 3;
    int nsub = NHIST >> 3;
    int lo = p * step, hi = lo + step;
    int stride = nsub * 256;
    for (int e = sub * 256 + tid; e < E; e += stride) {
      int d = dstE[e];
      if (d >= lo && d < hi) atomicAdd(&deg[d], 1);
    }
    return;
  }

  constexpr int KS = FIN / 32;  // k-steps of 32

  const int w    = tid >> 6;    // wave 0..3 -> rows [w*16, w*16+16)
  const int lane = tid & 63;
  const int cl   = lane & 15;   // A-row / D-col within tile
  const int grp  = lane >> 4;   // k-group / D-row-group
  const int n0   = blockIdx.x * 64;

  // ---- A fragments: load 8 contiguous fp32 of x, convert to bf16 ----
  const int arow = n0 + w * 16 + cl;
  const bool avalid = arow < N;
  short8 afrag[KS];
#pragma unroll
  for (int ks = 0; ks < KS; ++ks) {
    float4 v0 = make_float4(0.f, 0.f, 0.f, 0.f), v1 = v0;
    if (avalid) {
      const float4* xp =
          (const float4*)(x + (size_t)arow * FIN + ks * 32 + grp * 8);
      v0 = xp[0];
      v1 = xp[1];
    }
    union { short8 s8; unsigned u[4]; } af;
    af.u[0] = f2bf(v0.x) | (f2bf(v0.y) << 16);
    af.u[1] = f2bf(v0.z) | (f2bf(v0.w) << 16);
    af.u[2] = f2bf(v1.x) | (f2bf(v1.y) << 16);
    af.u[3] = f2bf(v1.z) | (f2bf(v1.w) << 16);
    afrag[ks] = af.s8;
  }

  // ---- MFMA main: 8 col-tiles x KS k-steps; B-frags from bf16 W copy ----
  f32x4 acc[8];
#pragma unroll
  for (int ct = 0; ct < 8; ++ct) acc[ct] = (f32x4){0.f, 0.f, 0.f, 0.f};

#pragma unroll
  for (int ks = 0; ks < KS; ++ks) {
#pragma unroll
    for (int ct = 0; ct < 8; ++ct) {
      short8 bfrag = *(const short8*)(Wb + (size_t)(ct * 16 + cl) * FIN +
                                      ks * 32 + grp * 8);
      acc[ct] = __builtin_amdgcn_mfma_f32_16x16x32_bf16(afrag[ks], bfrag,
                                                        acc[ct], 0, 0, 0);
    }
  }

  // ---- epilogue: fused attention scores + packed bf16x2 h ----
  // lane's cols: head0 -> ct*16+cl (ct 0..3), head1 -> (ct-4)*16+cl (ct 4..7)
  float ai[8], aj[8];
#pragma unroll
  for (int ct = 0; ct < 8; ++ct) {
    int hd = ct >> 2;
    int cw = (ct & 3) * 16 + cl;
    ai[ct] = att[hd * 128 + cw];
    aj[ct] = att[hd * 128 + 64 + cw];
  }

#pragma unroll
  for (int r = 0; r < 4; ++r) {
    int node = n0 + w * 16 + grp * 4 + r;  // D row for this reg
    float s0i = 0.f, s0j = 0.f, s1i = 0.f, s1j = 0.f;
    unsigned wpk[4];
#pragma unroll
    for (int ct = 0; ct < 4; ++ct) {
      float v0 = acc[ct][r];      // head0, col ct*16+cl
      float v1 = acc[ct + 4][r];  // head1, same channel
      s0i += v0 * ai[ct];
      s0j += v0 * aj[ct];
      s1i += v1 * ai[ct + 4];
      s1j += v1 * aj[ct + 4];
      wpk[ct] = f2bf(v0) | (f2bf(v1) << 16);
    }
    // reduce the 16 channel-lanes of this group
#pragma unroll
    for (int off = 8; off; off >>= 1) {
      s0i += __shfl_xor(s0i, off, 64);
      s0j += __shfl_xor(s0j, off, 64);
      s1i += __shfl_xor(s1i, off, 64);
      s1j += __shfl_xor(s1j, off, 64);
    }
    if (node < N) {
#pragma unroll
      for (int ct = 0; ct < 4; ++ct)
        hq[(size_t)node * 64 + ct * 16 + cl] = wpk[ct];
      if (cl == 0) {
        si[node * 2 + 0] = s0i;
        si[node * 2 + 1] = s1i;
        sj[node * 2 + 0] = s0j;
        sj[node * 2 + 1] = s1j;
      }
    }
  }
}

// edge-parallel Z sum over the ORIGINAL edge list incl. self-loops
__device__ __forceinline__ void z_edge_body(
    const int* __restrict__ srcE, const int* __restrict__ dstE,
    const float2* __restrict__ si2, const float2* __restrict__ sj2,
    float* __restrict__ Zp, int E, int Etot, int tid0, int stride) {
  float z0 = 0.f, z1 = 0.f;
  for (int e = tid0; e < Etot; e += stride) {
    int s, d;
    if (e < E) { s = srcE[e]; d = dstE[e]; } else { s = d = e - E; }
    float2 siv = si2[d];
    float2 sjv = sj2[s];
    float a0 = siv.x + sjv.x;
    float a1 = siv.y + sjv.y;
    a0 = a0 >= 0.f ? a0 : 0.2f * a0;
    a1 = a1 >= 0.f ? a1 : 0.2f * a1;
    z0 += __expf(a0); z1 += __expf(a1);
  }
  __shared__ float r0[4], r1[4];
  int lane = threadIdx.x & 63, w = threadIdx.x >> 6;
#pragma unroll
  for (int off = 32; off; off >>= 1) {
    z0 += __shfl_down(z0, off, 64);
    z1 += __shfl_down(z1, off, 64);
  }
  if (lane == 0) { r0[w] = z0; r1[w] = z1; }
  __syncthreads();
  if (threadIdx.x == 0) {
    atomicAdd(&Zp[0], r0[0] + r0[1] + r0[2] + r0[3]);
    atomicAdd(&Zp[1], r1[0] + r1[1] + r1[2] + r1[3]);
  }
}

__global__ __launch_bounds__(256) void z_edge(
    const int* __restrict__ srcE, const int* __restrict__ dstE,
    const float2* __restrict__ si2, const float2* __restrict__ sj2,
    float* __restrict__ Zp, int E, int Etot) {
  z_edge_body(srcE, dstE, si2, sj2, Zp, E, Etot,
              blockIdx.x * 256 + threadIdx.x, gridDim.x * 256);
}

__global__ __launch_bounds__(256) void scan_blocks(
    const int* __restrict__ deg, int* __restrict__ rowptr,
    int* __restrict__ bsum, int N) {
  __shared__ int ts[256];
  int b = blockIdx.x, t = threadIdx.x;
  int base = b * 1024 + t * 4;
  int v[4];
#pragma unroll
  for (int j = 0; j < 4; ++j) v[j] = (base + j < N) ? deg[base + j] : 0;
  int tot = v[0] + v[1] + v[2] + v[3];
  ts[t] = tot;
  __syncthreads();
#pragma unroll
  for (int off = 1; off < 256; off <<= 1) {
    int x = (t >= off) ? ts[t - off] : 0;
    __syncthreads();
    ts[t] += x;
    __syncthreads();
  }
  int run = ts[t] - tot;
#pragma unroll
  for (int j = 0; j < 4; ++j) {
    if (base + j < N) rowptr[base + j] = run;
    run += v[j];
  }
  if (t == 255) bsum[b] = ts[255];
}

// folds the bsum scan in: serial prefix of bsum (nb<=256) in LDS per block
__global__ __launch_bounds__(256) void scan_finish(
    int* __restrict__ rowptr, const int* __restrict__ bsum,
    int* __restrict__ cursor, int N, int Eall, int nb) {
  __shared__ int pre[256];
  if (threadIdx.x == 0) {
    int run = 0;
    for (int i = 0; i < nb; ++i) { pre[i] = run; run += bsum[i]; }
  }
  __syncthreads();
  int tid = blockIdx.x * blockDim.x + threadIdx.x;
  int stride = gridDim.x * blockDim.x;
  for (int i = tid; i < N; i += stride) {
    int v = rowptr[i] + pre[i >> 10];
    rowptr[i] = v;
    cursor[i] = v;
  }
  if (tid == 0) rowptr[N] = Eall;
}

// blocks[0,NZ): z1 edge-parallel (dispatched FIRST -> co-schedules under
// the scatter); blocks[NZ,NZ+NSCAT): dst-partitioned scatter (%8 affine).
__global__ __launch_bounds__(256) void scatter_z(
    const int* __restrict__ srcE, const int* __restrict__ dstE,
    int* __restrict__ cursor, int* __restrict__ esrc,
    const float2* __restrict__ si2, const float2* __restrict__ sj2,
    float* __restrict__ Zp, int E, int Etot, int step) {
  if ((int)blockIdx.x < NZ) {
    z_edge_body(srcE, dstE, si2, sj2, Zp, E, Etot,
                blockIdx.x * 256 + threadIdx.x, NZ * 256);
    return;
  }
  const int bid = blockIdx.x - NZ;
  const int p = bid & 7;
  const int sub = bid >> 3;
  const int nsub = NSCAT >> 3;
  const int lo = p * step;
  const int hi = lo + step;
  int stride = nsub * 256;
  for (int e = sub * 256 + threadIdx.x; e < E; e += stride) {
    int d = dstE[e];
    if (d >= lo && d < hi) {
      int s = srcE[e];
      int pos = atomicAdd(&cursor[d], 1);
      esrc[pos] = s;
    }
  }
}

// one wave per dst node (scalarized): inline attention weights, inline
// self-loop term, acc += w * hq[src], fused head-mean + bias (+relu)
__global__ __launch_bounds__(256) void csr_aggregate(
    const int* __restrict__ rowptr, const int* __restrict__ esrc,
    const unsigned* __restrict__ hq, const float2* __restrict__ si2,
    const float2* __restrict__ sj2, const float* __restrict__ Zp,
    const float* __restrict__ bias, float* __restrict__ out,
    int N, int do_relu) {
  int lane = threadIdx.x & 63;
  int wid = (blockIdx.x * blockDim.x + threadIdx.x) >> 6;
  int nw = (gridDim.x * blockDim.x) >> 6;
  float z0 = 1.f / (Zp[0] + 1e-10f);
  float z1 = 1.f / (Zp[1] + 1e-10f);
  float bv = bias[lane];
  for (int n0 = wid; n0 < N; n0 += nw) {
    // n is wave-uniform; force SGPR so the rowptr/esrc/sj2 chain is scalar
    int n = __builtin_amdgcn_readfirstlane(n0);
    int beg = rowptr[n], end = rowptr[n + 1];
    float2 siv = si2[n];
    // self-loop term (src = dst = n)
    float acc0, acc1;
    {
      float2 jv = sj2[n];
      unsigned p = hq[(size_t)n * 64 + lane];
      float a0 = siv.x + jv.x, a1 = siv.y + jv.y;
      a0 = a0 >= 0.f ? a0 : 0.2f * a0;
      a1 = a1 >= 0.f ? a1 : 0.2f * a1;
      acc0 = bflo(p) * __expf(a0);
      acc1 = bfhi(p) * __expf(a1);
    }
    int k = beg;
    for (; k + 4 <= end; k += 4) {
      int s0 = esrc[k], s1 = esrc[k + 1], s2 = esrc[k + 2], s3 = esrc[k + 3];
      float2 j0 = sj2[s0], j1 = sj2[s1], j2 = sj2[s2], j3 = sj2[s3];
      unsigned p0 = hq[(size_t)s0 * 64 + lane];
      unsigned p1 = hq[(size_t)s1 * 64 + lane];
      unsigned p2 = hq[(size_t)s2 * 64 + lane];
      unsigned p3 = hq[(size_t)s3 * 64 + lane];
      float a00 = siv.x + j0.x, a01 = siv.y + j0.y;
      float a10 = siv.x + j1.x, a11 = siv.y + j1.y;
      float a20 = siv.x + j2.x, a21 = siv.y + j2.y;
      float a30 = siv.x + j3.x, a31 = siv.y + j3.y;
      a00 = a00 >= 0.f ? a00 : 0.2f * a00;  a01 = a01 >= 0.f ? a01 : 0.2f * a01;
      a10 = a10 >= 0.f ? a10 : 0.2f * a10;  a11 = a11 >= 0.f ? a11 : 0.2f * a11;
      a20 = a20 >= 0.f ? a20 : 0.2f * a20;  a21 = a21 >= 0.f ? a21 : 0.2f * a21;
      a30 = a30 >= 0.f ? a30 : 0.2f * a30;  a31 = a31 >= 0.f ? a31 : 0.2f * a31;
      float w00 = __expf(a00), w01 = __expf(a01);
      float w10 = __expf(a10), w11 = __expf(a11);
      float w20 = __expf(a20), w21 = __expf(a21);
      float w30 = __expf(a30), w31 = __expf(a31);
      acc0 += bflo(p0) * w00 + bflo(p1) * w10 + bflo(p2) * w20 + bflo(p3) * w30;
      acc1 += bfhi(p0) * w01 + bfhi(p1) * w11 + bfhi(p2) * w21 + bfhi(p3) * w31;
    }
    for (; k < end; ++k) {
      int s = esrc[k];
      float2 jv = sj2[s];
      unsigned p = hq[(size_t)s * 64 + lane];
      float a0 = siv.x + jv.x, a1 = siv.y + jv.y;
      a0 = a0 >= 0.f ? a0 : 0.2f * a0;
      a1 = a1 >= 0.f ? a1 : 0.2f * a1;
      acc0 += bflo(p) * __expf(a0);
      acc1 += bfhi(p) * __expf(a1);
    }
    float r = 0.5f * (acc0 * z0 + acc1 * z1) + bv;
    if (do_relu) r = fmaxf(r, 0.f);
    out[(size_t)n * 64 + lane] = r;
  }
}

extern "C" void kernel_launch(void* const* d_in, const int* in_sizes, int n_in,
                              void* d_out, int out_size, void* d_ws, size_t ws_size,
                              hipStream_t stream) {
  const float* x    = (const float*)d_in[0];
  const int*   ei   = (const int*)d_in[1];   // [2, E] int32
  const float* W1   = (const float*)d_in[2];
  const float* att1 = (const float*)d_in[3];
  const float* b1   = (const float*)d_in[4];
  const float* W2   = (const float*)d_in[5];
  const float* att2 = (const float*)d_in[6];
  const float* b2   = (const float*)d_in[7];
  float* out = (float*)d_out;

  const int N = in_sizes[0] / 128;   // 50000
  const int E = in_sizes[1] / 2;     // 800000
  const int Etot = E + N;            // incl. self-loops (Z sums only)
  const int* srcE = ei;
  const int* dstE = ei + E;

  // workspace layout (all segments 16B-aligned)
  unsigned* hq = (unsigned*)d_ws;                 // N*64 packed bf16x2
  float* si    = (float*)(hq + (size_t)N * 64);   // N*2
  float* sj    = si + (size_t)N * 2;              // N*2
  float* Z     = sj + (size_t)N * 2;              // 4 (L1: Z[0..1], L2: Z[2..3])
  unsigned short* wbf1 = (unsigned short*)(Z + 4);  // 128*128 bf16 W1
  unsigned short* wbf2 = wbf1 + 128 * 128;          // 128*64 bf16 W2
  float* x2    = (float*)(wbf2 + 128 * 64);       // N*64
  int* rowptr  = (int*)(x2 + (size_t)N * 64);     // N+1
  int* cursor  = rowptr + (N + 1);                // N (deg histogram too)
  int* esrc    = cursor + N;                      // E (real edges only)
  int* bsum    = esrc + E;                        // up to 256

  dim3 blk(256);
  int nb = (N + 1023) / 1024;
  int ntiles = (N + 63) / 64;
  int step = (N + 7) / 8;

  // 0) zero cursor/Z + W->bf16 conversion (replaces memset)
  init_ws<<<128, blk, 0, stream>>>(W1, W2, wbf1, wbf2, cursor, Z, N);
  // 1) gemm1 (MFMA) + dst-histogram fused
  gemm_mfma<128><<<ntiles + NHIST, blk, 0, stream>>>(
      x, wbf1, att1, hq, si, sj, N, dstE, cursor, E, ntiles, step);
  // 2,3) rowptr prefix
  scan_blocks<<<nb, blk, 0, stream>>>(cursor, rowptr, bsum, N);
  scan_finish<<<256, blk, 0, stream>>>(rowptr, bsum, cursor, N, E, nb);
  // 4) z1 (first 256 blocks, co-scheduled) + scatter (1792 blocks)
  scatter_z<<<NZ + NSCAT, blk, 0, stream>>>(
      srcE, dstE, cursor, esrc, (const float2*)si, (const float2*)sj,
      Z, E, Etot, step);
  // 5) layer-1 aggregation -> x2 (self-loop inline; relu fused)
  csr_aggregate<<<4096, blk, 0, stream>>>(rowptr, esrc, hq, (const float2*)si,
                                          (const float2*)sj, Z, b1, x2, N, 1);
  // 6) gemm2 (MFMA, grid=ntiles: hist branch never taken)
  gemm_mfma<64><<<ntiles, blk, 0, stream>>>(
      x2, wbf2, att2, hq, si, sj, N, dstE, cursor, E, ntiles, step);
  // 7) z2
  z_edge<<<NZ, blk, 0, stream>>>(srcE, dstE, (const float2*)si,
                                 (const float2*)sj, Z + 2, E, Etot);
  // 8) layer-2 aggregation -> out
  csr_aggregate<<<4096, blk, 0, stream>>>(rowptr, esrc, hq, (const float2*)si,
                                          (const float2*)sj, Z + 2, b2, out, N, 0);
}

// Round 2
// 283.074 us; speedup vs baseline: 1.0582x; 1.0502x over previous
//
#include <hip/hip_runtime.h>
#include <hip/hip_bf16.h>
#include <math.h>

// ---------------------------------------------------------------------------
// GAT 2-layer forward. CSR aggregation, bf16 gather table, inline attention
// weights. bf16 MFMA GEMM with W staged in LDS (XOR-swizzled 16B chunks):
//
//   0) init_ws: zero cursor + Z
//   1) gemm_mfma<128>: blocks[0,ntiles) = MFMA gemm1. W1 (fp32) converted to
//      bf16 and staged into 32KB LDS once per block; inner loop is
//      ds_read_b128 -> mfma_16x16x32_bf16 (compiler-scheduled lgkmcnt).
//      blocks[ntiles,+1264) = dst-histogram over real edges.
//   2) scan_blocks, 3) scan_finish (rowptr prefix; cursor copy)
//   4) scatter_z: blocks[0,256)=z1 edge-parallel; rest dst-partitioned scatter
//   5) csr_aggregate -> x2 (self-loop term inline; relu fused)
//   6) gemm_mfma<64> grid=ntiles (pure gemm2, 16KB LDS)
//   7) z_edge -> Z[2..3]
//   8) csr_aggregate -> out
//
// MFMA layout (HW-verified m89): A: lane holds A[l&15][(l>>4)*8+j];
// B: B[(l>>4)*8+j][l&15]; D: row=(l>>4)*4+reg, col=l&15.
// LDS swizzle: W row r, 16B-chunk c stored at chunk position c ^ (r & CPR-1).
// Read of (ct*16+cl, ks*4+grp) then hits bank-uniform sets (2 lanes/quad).
// ---------------------------------------------------------------------------

#define NHIST 1264   // 8*158
#define NZ    256
#define NSCAT 1792   // 8*224

using short8 = __attribute__((ext_vector_type(8))) short;
using f32x4  = __attribute__((ext_vector_type(4))) float;

__device__ __forceinline__ unsigned f2bf(float x) {  // fp32 -> bf16 (RNE)
  unsigned u = __float_as_uint(x);
  return (u + 0x7fffu + ((u >> 16) & 1u)) >> 16;
}
__device__ __forceinline__ float bflo(unsigned p) { return __uint_as_float(p << 16); }
__device__ __forceinline__ float bfhi(unsigned p) { return __uint_as_float(p & 0xffff0000u); }

// zero the cursor/deg array + Z accumulators
__global__ __launch_bounds__(256) void init_ws(
    int* __restrict__ cursor, float* __restrict__ Z, int N) {
  int tid = blockIdx.x * 256 + threadIdx.x;
  int stride = gridDim.x * 256;
  for (int i = tid; i < N; i += stride) cursor[i] = 0;
  if (tid < 4) Z[tid] = 0.f;
}

// MFMA GEMM (h = x @ W^T) + fused attention scores + bf16 pack.
// W staged in LDS (bf16, XOR-swizzled). blocks >= ntiles run dst-histogram.
template <int FIN>
__global__ __launch_bounds__(256) void gemm_mfma(
    const float* __restrict__ x, const float* __restrict__ W,
    const float* __restrict__ att, unsigned* __restrict__ hq,
    float* __restrict__ si, float* __restrict__ sj,
    int N,
    const int* __restrict__ dstE, int* __restrict__ deg,
    int E, int ntiles, int step) {
  const int tid = threadIdx.x;

  if ((int)blockIdx.x >= ntiles) {
    // ---- histogram over real edges (dst-partitioned, %8 XCD-affine) ----
    int bid = blockIdx.x - ntiles;
    int p = bid & 7, sub = bid >> 3;
    int nsub = NHIST >> 3;
    int lo = p * step, hi = lo + step;
    int stride = nsub * 256;
    for (int e = sub * 256 + tid; e < E; e += stride) {
      int d = dstE[e];
      if (d >= lo && d < hi) atomicAdd(&deg[d], 1);
    }
    return;
  }

  constexpr int KS = FIN / 32;        // k-steps of 32
  constexpr int CPR = FIN / 8;        // 16B chunks per W row
  constexpr int NCHUNK = 128 * CPR;   // total 16B chunks (128 out-cols)

  __shared__ unsigned short wlds[128 * FIN];  // bf16 W, swizzled

  const int w    = tid >> 6;    // wave 0..3 -> rows [w*16, w*16+16)
  const int lane = tid & 63;
  const int cl   = lane & 15;   // A-row / D-col within tile
  const int grp  = lane >> 4;   // k-group / D-row-group
  const int n0   = blockIdx.x * 64;

  // ---- issue A loads early (fp32 x, 8 contiguous floats per ks) ----
  const int arow = n0 + w * 16 + cl;
  const bool avalid = arow < N;
  float4 av0[KS], av1[KS];
#pragma unroll
  for (int ks = 0; ks < KS; ++ks) {
    av0[ks] = make_float4(0.f, 0.f, 0.f, 0.f);
    av1[ks] = av0[ks];
    if (avalid) {
      const float4* xp =
          (const float4*)(x + (size_t)arow * FIN + ks * 32 + grp * 8);
      av0[ks] = xp[0];
      av1[ks] = xp[1];
    }
  }

  // ---- stage W -> LDS as bf16, XOR-swizzled 16B chunks ----
  const float4* W4 = (const float4*)W;
  for (int c = tid; c < NCHUNK; c += 256) {
    int row = c / CPR;           // CPR is pow2 -> shift
    int cc  = c & (CPR - 1);
    float4 lo = W4[c * 2];
    float4 hi = W4[c * 2 + 1];
    unsigned short* dst = &wlds[row * FIN + ((cc ^ (row & (CPR - 1))) * 8)];
    *(uint4*)dst = make_uint4(
        f2bf(lo.x) | (f2bf(lo.y) << 16), f2bf(lo.z) | (f2bf(lo.w) << 16),
        f2bf(hi.x) | (f2bf(hi.y) << 16), f2bf(hi.z) | (f2bf(hi.w) << 16));
  }
  __syncthreads();

  // ---- convert A to bf16 fragments ----
  short8 afrag[KS];
#pragma unroll
  for (int ks = 0; ks < KS; ++ks) {
    union { short8 s8; unsigned u[4]; } af;
    af.u[0] = f2bf(av0[ks].x) | (f2bf(av0[ks].y) << 16);
    af.u[1] = f2bf(av0[ks].z) | (f2bf(av0[ks].w) << 16);
    af.u[2] = f2bf(av1[ks].x) | (f2bf(av1[ks].y) << 16);
    af.u[3] = f2bf(av1[ks].z) | (f2bf(av1[ks].w) << 16);
    afrag[ks] = af.s8;
  }

  // ---- MFMA main: 8 col-tiles x KS k-steps; B-frags from LDS ----
  f32x4 acc[8];
#pragma unroll
  for (int ct = 0; ct < 8; ++ct) acc[ct] = (f32x4){0.f, 0.f, 0.f, 0.f};

  const int swz = cl & (CPR - 1);  // (ct*16+cl) & (CPR-1) == cl & (CPR-1)
#pragma unroll
  for (int ks = 0; ks < KS; ++ks) {
#pragma unroll
    for (int ct = 0; ct < 8; ++ct) {
      const unsigned short* bp =
          &wlds[(ct * 16 + cl) * FIN + (((ks * 4 + grp) ^ swz) * 8)];
      short8 bfrag = *(const short8*)bp;
      acc[ct] = __builtin_amdgcn_mfma_f32_16x16x32_bf16(afrag[ks], bfrag,
                                                        acc[ct], 0, 0, 0);
    }
  }

  // ---- epilogue: fused attention scores + packed bf16x2 h ----
  // lane's cols: head0 -> ct*16+cl (ct 0..3), head1 -> (ct-4)*16+cl (ct 4..7)
  float ai[8], aj[8];
#pragma unroll
  for (int ct = 0; ct < 8; ++ct) {
    int hd = ct >> 2;
    int cw = (ct & 3) * 16 + cl;
    ai[ct] = att[hd * 128 + cw];
    aj[ct] = att[hd * 128 + 64 + cw];
  }

#pragma unroll
  for (int r = 0; r < 4; ++r) {
    int node = n0 + w * 16 + grp * 4 + r;  // D row for this reg
    float s0i = 0.f, s0j = 0.f, s1i = 0.f, s1j = 0.f;
    unsigned wpk[4];
#pragma unroll
    for (int ct = 0; ct < 4; ++ct) {
      float v0 = acc[ct][r];      // head0, col ct*16+cl
      float v1 = acc[ct + 4][r];  // head1, same channel
      s0i += v0 * ai[ct];
      s0j += v0 * aj[ct];
      s1i += v1 * ai[ct + 4];
      s1j += v1 * aj[ct + 4];
      wpk[ct] = f2bf(v0) | (f2bf(v1) << 16);
    }
    // reduce the 16 channel-lanes of this group
#pragma unroll
    for (int off = 8; off; off >>= 1) {
      s0i += __shfl_xor(s0i, off, 64);
      s0j += __shfl_xor(s0j, off, 64);
      s1i += __shfl_xor(s1i, off, 64);
      s1j += __shfl_xor(s1j, off, 64);
    }
    if (node < N) {
#pragma unroll
      for (int ct = 0; ct < 4; ++ct)
        hq[(size_t)node * 64 + ct * 16 + cl] = wpk[ct];
      if (cl == 0) {
        si[node * 2 + 0] = s0i;
        si[node * 2 + 1] = s1i;
        sj[node * 2 + 0] = s0j;
        sj[node * 2 + 1] = s1j;
      }
    }
  }
}

// edge-parallel Z sum over the ORIGINAL edge list incl. self-loops
__device__ __forceinline__ void z_edge_body(
    const int* __restrict__ srcE, const int* __restrict__ dstE,
    const float2* __restrict__ si2, const float2* __restrict__ sj2,
    float* __restrict__ Zp, int E, int Etot, int tid0, int stride) {
  float z0 = 0.f, z1 = 0.f;
  for (int e = tid0; e < Etot; e += stride) {
    int s, d;
    if (e < E) { s = srcE[e]; d = dstE[e]; } else { s = d = e - E; }
    float2 siv = si2[d];
    float2 sjv = sj2[s];
    float a0 = siv.x + sjv.x;
    float a1 = siv.y + sjv.y;
    a0 = a0 >= 0.f ? a0 : 0.2f * a0;
    a1 = a1 >= 0.f ? a1 : 0.2f * a1;
    z0 += __expf(a0); z1 += __expf(a1);
  }
  __shared__ float r0[4], r1[4];
  int lane = threadIdx.x & 63, w = threadIdx.x >> 6;
#pragma unroll
  for (int off = 32; off; off >>= 1) {
    z0 += __shfl_down(z0, off, 64);
    z1 += __shfl_down(z1, off, 64);
  }
  if (lane == 0) { r0[w] = z0; r1[w] = z1; }
  __syncthreads();
  if (threadIdx.x == 0) {
    atomicAdd(&Zp[0], r0[0] + r0[1] + r0[2] + r0[3]);
    atomicAdd(&Zp[1], r1[0] + r1[1] + r1[2] + r1[3]);
  }
}

__global__ __launch_bounds__(256) void z_edge(
    const int* __restrict__ srcE, const int* __restrict__ dstE,
    const float2* __restrict__ si2, const float2* __restrict__ sj2,
    float* __restrict__ Zp, int E, int Etot) {
  z_edge_body(srcE, dstE, si2, sj2, Zp, E, Etot,
              blockIdx.x * 256 + threadIdx.x, gridDim.x * 256);
}

__global__ __launch_bounds__(256) void scan_blocks(
    const int* __restrict__ deg, int* __restrict__ rowptr,
    int* __restrict__ bsum, int N) {
  __shared__ int ts[256];
  int b = blockIdx.x, t = threadIdx.x;
  int base = b * 1024 + t * 4;
  int v[4];
#pragma unroll
  for (int j = 0; j < 4; ++j) v[j] = (base + j < N) ? deg[base + j] : 0;
  int tot = v[0] + v[1] + v[2] + v[3];
  ts[t] = tot;
  __syncthreads();
#pragma unroll
  for (int off = 1; off < 256; off <<= 1) {
    int x = (t >= off) ? ts[t - off] : 0;
    __syncthreads();
    ts[t] += x;
    __syncthreads();
  }
  int run = ts[t] - tot;
#pragma unroll
  for (int j = 0; j < 4; ++j) {
    if (base + j < N) rowptr[base + j] = run;
    run += v[j];
  }
  if (t == 255) bsum[b] = ts[255];
}

// folds the bsum scan in: serial prefix of bsum (nb<=256) in LDS per block
__global__ __launch_bounds__(256) void scan_finish(
    int* __restrict__ rowptr, const int* __restrict__ bsum,
    int* __restrict__ cursor, int N, int Eall, int nb) {
  __shared__ int pre[256];
  if (threadIdx.x == 0) {
    int run = 0;
    for (int i = 0; i < nb; ++i) { pre[i] = run; run += bsum[i]; }
  }
  __syncthreads();
  int tid = blockIdx.x * blockDim.x + threadIdx.x;
  int stride = gridDim.x * blockDim.x;
  for (int i = tid; i < N; i += stride) {
    int v = rowptr[i] + pre[i >> 10];
    rowptr[i] = v;
    cursor[i] = v;
  }
  if (tid == 0) rowptr[N] = Eall;
}

// blocks[0,NZ): z1 edge-parallel (dispatched FIRST -> co-schedules under
// the scatter); blocks[NZ,NZ+NSCAT): dst-partitioned scatter (%8 affine).
__global__ __launch_bounds__(256) void scatter_z(
    const int* __restrict__ srcE, const int* __restrict__ dstE,
    int* __restrict__ cursor, int* __restrict__ esrc,
    const float2* __restrict__ si2, const float2* __restrict__ sj2,
    float* __restrict__ Zp, int E, int Etot, int step) {
  if ((int)blockIdx.x < NZ) {
    z_edge_body(srcE, dstE, si2, sj2, Zp, E, Etot,
                blockIdx.x * 256 + threadIdx.x, NZ * 256);
    return;
  }
  const int bid = blockIdx.x - NZ;
  const int p = bid & 7;
  const int sub = bid >> 3;
  const int nsub = NSCAT >> 3;
  const int lo = p * step;
  const int hi = lo + step;
  int stride = nsub * 256;
  for (int e = sub * 256 + threadIdx.x; e < E; e += stride) {
    int d = dstE[e];
    if (d >= lo && d < hi) {
      int s = srcE[e];
      int pos = atomicAdd(&cursor[d], 1);
      esrc[pos] = s;
    }
  }
}

// one wave per dst node (scalarized): inline attention weights, inline
// self-loop term, acc += w * hq[src], fused head-mean + bias (+relu)
__global__ __launch_bounds__(256) void csr_aggregate(
    const int* __restrict__ rowptr, const int* __restrict__ esrc,
    const unsigned* __restrict__ hq, const float2* __restrict__ si2,
    const float2* __restrict__ sj2, const float* __restrict__ Zp,
    const float* __restrict__ bias, float* __restrict__ out,
    int N, int do_relu) {
  int lane = threadIdx.x & 63;
  int wid = (blockIdx.x * blockDim.x + threadIdx.x) >> 6;
  int nw = (gridDim.x * blockDim.x) >> 6;
  float z0 = 1.f / (Zp[0] + 1e-10f);
  float z1 = 1.f / (Zp[1] + 1e-10f);
  float bv = bias[lane];
  for (int n0 = wid; n0 < N; n0 += nw) {
    // n is wave-uniform; force SGPR so the rowptr/esrc/sj2 chain is scalar
    int n = __builtin_amdgcn_readfirstlane(n0);
    int beg = rowptr[n], end = rowptr[n + 1];
    float2 siv = si2[n];
    // self-loop term (src = dst = n)
    float acc0, acc1;
    {
      float2 jv = sj2[n];
      unsigned p = hq[(size_t)n * 64 + lane];
      float a0 = siv.x + jv.x, a1 = siv.y + jv.y;
      a0 = a0 >= 0.f ? a0 : 0.2f * a0;
      a1 = a1 >= 0.f ? a1 : 0.2f * a1;
      acc0 = bflo(p) * __expf(a0);
      acc1 = bfhi(p) * __expf(a1);
    }
    int k = beg;
    for (; k + 4 <= end; k += 4) {
      int s0 = esrc[k], s1 = esrc[k + 1], s2 = esrc[k + 2], s3 = esrc[k + 3];
      float2 j0 = sj2[s0], j1 = sj2[s1], j2 = sj2[s2], j3 = sj2[s3];
      unsigned p0 = hq[(size_t)s0 * 64 + lane];
      unsigned p1 = hq[(size_t)s1 * 64 + lane];
      unsigned p2 = hq[(size_t)s2 * 64 + lane];
      unsigned p3 = hq[(size_t)s3 * 64 + lane];
      float a00 = siv.x + j0.x, a01 = siv.y + j0.y;
      float a10 = siv.x + j1.x, a11 = siv.y + j1.y;
      float a20 = siv.x + j2.x, a21 = siv.y + j2.y;
      float a30 = siv.x + j3.x, a31 = siv.y + j3.y;
      a00 = a00 >= 0.f ? a00 : 0.2f * a00;  a01 = a01 >= 0.f ? a01 : 0.2f * a01;
      a10 = a10 >= 0.f ? a10 : 0.2f * a10;  a11 = a11 >= 0.f ? a11 : 0.2f * a11;
      a20 = a20 >= 0.f ? a20 : 0.2f * a20;  a21 = a21 >= 0.f ? a21 : 0.2f * a21;
      a30 = a30 >= 0.f ? a30 : 0.2f * a30;  a31 = a31 >= 0.f ? a31 : 0.2f * a31;
      float w00 = __expf(a00), w01 = __expf(a01);
      float w10 = __expf(a10), w11 = __expf(a11);
      float w20 = __expf(a20), w21 = __expf(a21);
      float w30 = __expf(a30), w31 = __expf(a31);
      acc0 += bflo(p0) * w00 + bflo(p1) * w10 + bflo(p2) * w20 + bflo(p3) * w30;
      acc1 += bfhi(p0) * w01 + bfhi(p1) * w11 + bfhi(p2) * w21 + bfhi(p3) * w31;
    }
    for (; k < end; ++k) {
      int s = esrc[k];
      float2 jv = sj2[s];
      unsigned p = hq[(size_t)s * 64 + lane];
      float a0 = siv.x + jv.x, a1 = siv.y + jv.y;
      a0 = a0 >= 0.f ? a0 : 0.2f * a0;
      a1 = a1 >= 0.f ? a1 : 0.2f * a1;
      acc0 += bflo(p) * __expf(a0);
      acc1 += bfhi(p) * __expf(a1);
    }
    float r = 0.5f * (acc0 * z0 + acc1 * z1) + bv;
    if (do_relu) r = fmaxf(r, 0.f);
    out[(size_t)n * 64 + lane] = r;
  }
}

extern "C" void kernel_launch(void* const* d_in, const int* in_sizes, int n_in,
                              void* d_out, int out_size, void* d_ws, size_t ws_size,
                              hipStream_t stream) {
  const float* x    = (const float*)d_in[0];
  const int*   ei   = (const int*)d_in[1];   // [2, E] int32
  const float* W1   = (const float*)d_in[2];
  const float* att1 = (const float*)d_in[3];
  const float* b1   = (const float*)d_in[4];
  const float* W2   = (const float*)d_in[5];
  const float* att2 = (const float*)d_in[6];
  const float* b2   = (const float*)d_in[7];
  float* out = (float*)d_out;

  const int N = in_sizes[0] / 128;   // 50000
  const int E = in_sizes[1] / 2;     // 800000
  const int Etot = E + N;            // incl. self-loops (Z sums only)
  const int* srcE = ei;
  const int* dstE = ei + E;

  // workspace layout (all segments 16B-aligned)
  unsigned* hq = (unsigned*)d_ws;                 // N*64 packed bf16x2
  float* si    = (float*)(hq + (size_t)N * 64);   // N*2
  float* sj    = si + (size_t)N * 2;              // N*2
  float* Z     = sj + (size_t)N * 2;              // 4 (L1: Z[0..1], L2: Z[2..3])
  float* x2    = Z + 4;                           // N*64
  int* rowptr  = (int*)(x2 + (size_t)N * 64);     // N+1
  int* cursor  = rowptr + (N + 1);                // N (deg histogram too)
  int* esrc    = cursor + N;                      // E (real edges only)
  int* bsum    = esrc + E;                        // up to 256

  dim3 blk(256);
  int nb = (N + 1023) / 1024;
  int ntiles = (N + 63) / 64;
  int step = (N + 7) / 8;

  // 0) zero cursor/Z
  init_ws<<<128, blk, 0, stream>>>(cursor, Z, N);
  // 1) gemm1 (MFMA, LDS-staged W) + dst-histogram fused
  gemm_mfma<128><<<ntiles + NHIST, blk, 0, stream>>>(
      x, W1, att1, hq, si, sj, N, dstE, cursor, E, ntiles, step);
  // 2,3) rowptr prefix
  scan_blocks<<<nb, blk, 0, stream>>>(cursor, rowptr, bsum, N);
  scan_finish<<<256, blk, 0, stream>>>(rowptr, bsum, cursor, N, E, nb);
  // 4) z1 (first 256 blocks, co-scheduled) + scatter (1792 blocks)
  scatter_z<<<NZ + NSCAT, blk, 0, stream>>>(
      srcE, dstE, cursor, esrc, (const float2*)si, (const float2*)sj,
      Z, E, Etot, step);
  // 5) layer-1 aggregation -> x2 (self-loop inline; relu fused)
  csr_aggregate<<<4096, blk, 0, stream>>>(rowptr, esrc, hq, (const float2*)si,
                                          (const float2*)sj, Z, b1, x2, N, 1);
  // 6) gemm2 (MFMA, grid=ntiles: hist branch never taken)
  gemm_mfma<64><<<ntiles, blk, 0, stream>>>(
      x2, W2, att2, hq, si, sj, N, dstE, cursor, E, ntiles, step);
  // 7) z2
  z_edge<<<NZ, blk, 0, stream>>>(srcE, dstE, (const float2*)si,
                                 (const float2*)sj, Z + 2, E, Etot);
  // 8) layer-2 aggregation -> out
  csr_aggregate<<<4096, blk, 0, stream>>>(rowptr, esrc, hq, (const float2*)si,
                                          (const float2*)sj, Z + 2, b2, out, N, 0);
}